// Round 2
// baseline (1714.551 us; speedup 1.0000x reference)
//
#include <hip/hip_runtime.h>
#include <cstdint>

using short8 = __attribute__((ext_vector_type(8))) short;
using f32x4  = __attribute__((ext_vector_type(4))) float;

// ---------- helpers ----------
__device__ __forceinline__ unsigned short bf16rne(float f) {
  unsigned int u = __float_as_uint(f);
  unsigned int r = u + 0x7fffu + ((u >> 16) & 1u);
  return (unsigned short)(r >> 16);
}

__device__ __forceinline__ void gl2lds16(const void* g, void* s) {
  auto gp = reinterpret_cast<const __attribute__((address_space(1))) unsigned int*>(
      reinterpret_cast<uintptr_t>(g));
  auto sp = reinterpret_cast<__attribute__((address_space(3))) unsigned int*>(
      (uint32_t)reinterpret_cast<uintptr_t>(s));
  __builtin_amdgcn_global_load_lds(gp, sp, 16, 0, 0);
}

__device__ __forceinline__ float fast_tanh(float x) {
  float e = __expf(2.0f * x);
  return 1.0f - 2.0f / (e + 1.0f);
}

// ---------- K0: fold Wq = W_k @ q (bf16 [16][512]); Wvt = W_v^T (bf16 [1024][512]) ----------
__global__ __launch_bounds__(256) void prep_kernel(
    const float* __restrict__ Wk, const float* __restrict__ q,
    const float* __restrict__ Wv,
    unsigned short* __restrict__ wqb, unsigned short* __restrict__ wvt) {
  __shared__ float T[64 * 65];
  int bid = blockIdx.x;
  if (bid < 32) {
    int idx = bid * 256 + threadIdx.x;   // 0..8191
    int n = idx >> 9, c = idx & 511;
    const float* wrow = Wk + (long)c * 1024 + n * 64;
    const float* qrow = q + n * 64;
    float s = 0.f;
    #pragma unroll 8
    for (int k = 0; k < 64; ++k) s += wrow[k] * qrow[k];
    wqb[n * 512 + c] = bf16rne(s);
  } else {
    int t = bid - 32;                    // 0..127
    int tc = t & 7, tl = t >> 3;
    int c0 = tc * 64, l0 = tl * 64;
    int j = threadIdx.x & 63, i0 = threadIdx.x >> 6;
    #pragma unroll
    for (int ii = 0; ii < 16; ++ii) {
      int i = i0 * 16 + ii;
      T[i * 65 + j] = Wv[(long)(c0 + i) * 1024 + l0 + j];
    }
    __syncthreads();
    #pragma unroll
    for (int ii = 0; ii < 16; ++ii) {
      int jj = i0 * 16 + ii;
      wvt[(long)(l0 + jj) * 512 + c0 + j] = bf16rne(T[j * 65 + jj]);
    }
  }
}

// ---------- K2: fused cvt + dot, 1-barrier async pipeline (unchanged) ----------
__global__ __launch_bounds__(256) void dot_kernel(
    const float* __restrict__ kv, const unsigned short* __restrict__ wqb,
    unsigned short* __restrict__ xb, float* __restrict__ dotbuf) {
  __shared__ __align__(16) float AsF[2][128 * 64];          // 2 x 32 KB
  __shared__ __align__(16) unsigned short Ws[16 * 512];     // 16 KB
  int tid = threadIdx.x, l = tid & 63, w = tid >> 6;
  long row0 = (long)blockIdx.x * 128;
  int qd = l >> 4, lm = l & 15;

  for (int j = 0; j < 4; ++j) {
    int n = w * 4 + j;
    gl2lds16(wqb + n * 512 + ((l ^ (n & 7)) * 8), &Ws[n * 512]);
  }

  auto dmaA = [&](int it, int buf) {
    #pragma unroll
    for (int j = 0; j < 8; ++j) {
      int g = (w * 8 + j) * 64 + l;
      int r = g >> 4, c = g & 15;
      int cc = c ^ (r & 14);
      gl2lds16(kv + (row0 + r) * 512 + it * 64 + cc * 4, &AsF[buf][(w * 8 + j) * 256]);
    }
  };

  f32x4 acc[2];
  acc[0] = f32x4{0.f, 0.f, 0.f, 0.f};
  acc[1] = f32x4{0.f, 0.f, 0.f, 0.f};

  dmaA(0, 0);
  for (int it = 0; it < 8; ++it) {
    __syncthreads();
    if (it < 7) dmaA(it + 1, (it + 1) & 1);
    const float* base = &AsF[it & 1][0];
    #pragma unroll
    for (int mi = 0; mi < 2; ++mi) {
      int m = w * 32 + mi * 16 + lm;
      int s = m & 14;
      #pragma unroll
      for (int k32 = 0; k32 < 2; ++k32) {
        int fc = k32 * 8 + qd * 2;
        float4 fa = *(const float4*)&base[(m * 16 + (fc ^ s)) * 4];
        float4 fb = *(const float4*)&base[(m * 16 + ((fc + 1) ^ s)) * 4];
        short8 h;
        h[0] = bf16rne(fa.x); h[1] = bf16rne(fa.y); h[2] = bf16rne(fa.z); h[3] = bf16rne(fa.w);
        h[4] = bf16rne(fb.x); h[5] = bf16rne(fb.y); h[6] = bf16rne(fb.z); h[7] = bf16rne(fb.w);
        *(short8*)&xb[(row0 + m) * 512 + it * 64 + k32 * 32 + qd * 8] = h;
        int cl = it * 8 + k32 * 4 + qd;
        short8 bfrag = *(const short8*)&Ws[lm * 512 + ((cl ^ (lm & 7)) * 8)];
        acc[mi] = __builtin_amdgcn_mfma_f32_16x16x32_bf16(h, bfrag, acc[mi], 0, 0, 0);
      }
    }
  }
  #pragma unroll
  for (int mi = 0; mi < 2; ++mi) {
    long rg = row0 + w * 32 + mi * 16 + qd * 4;
    long b = rg >> 12;
    long s = rg & 4095;
    *(f32x4*)&dotbuf[((b * 16 + lm) << 12) + s] = acc[mi];
  }
}

// ---------- K3: softmax over s per (b,n), normalize in place (unchanged) ----------
__global__ __launch_bounds__(256) void softmax_kernel(float* __restrict__ dotbuf) {
  long bn = blockIdx.x;
  float4* p = (float4*)(dotbuf + bn * 4096);
  int tid = threadIdx.x;
  int l = tid & 63, w = tid >> 6;
  float4 v[4];
  float mx = -1e30f;
  #pragma unroll
  for (int i = 0; i < 4; ++i) {
    v[i] = p[tid + i * 256];
    mx = fmaxf(mx, fmaxf(fmaxf(v[i].x, v[i].y), fmaxf(v[i].z, v[i].w)));
  }
  for (int o = 32; o; o >>= 1) mx = fmaxf(mx, __shfl_xor(mx, o, 64));
  __shared__ float redm[4];
  __shared__ float reds[4];
  if (l == 0) redm[w] = mx;
  __syncthreads();
  mx = fmaxf(fmaxf(redm[0], redm[1]), fmaxf(redm[2], redm[3]));
  float s = 0.f;
  #pragma unroll
  for (int i = 0; i < 4; ++i) {
    v[i].x = __expf(v[i].x - mx); v[i].y = __expf(v[i].y - mx);
    v[i].z = __expf(v[i].z - mx); v[i].w = __expf(v[i].w - mx);
    s += v[i].x + v[i].y + v[i].z + v[i].w;
  }
  for (int o = 32; o; o >>= 1) s += __shfl_xor(s, o, 64);
  if (l == 0) reds[w] = s;
  __syncthreads();
  s = reds[0] + reds[1] + reds[2] + reds[3];
  float inv = 1.0f / s;
  #pragma unroll
  for (int i = 0; i < 4; ++i) {
    v[i].x *= inv; v[i].y *= inv; v[i].z *= inv; v[i].w *= inv;
    p[tid + i * 256] = v[i];
  }
}

// ---------- K4: value GEMM + tanh + weighted reduce ----------
// R2 STRUCTURE: occupancy fix. R0/R1 both sat at 8 waves/CU (2 waves/SIMD) and
// both scored ~200 us regardless of pipeline depth -> latency/stall-bound, not
// pipe-bound (real per-SIMD MfmaUtil ~8%). This version: 256x256 tile, 8 waves,
// BK=32, 2-slot double buffer = 68 KB LDS -> 2 blocks/CU = 16 waves/CU
// (4 waves/SIMD), twice the resident waves of R0/R1. Stage(t+1) issues right
// after the top-of-t barrier (slot safe: all reads of slot (t+1)&1 finished at
// that barrier), ~1 K-tile load lead. Inter-block overlap covers the per-block
// vmcnt(0) drains. All swizzle/fragment/epilogue math identical to verified R1.
__global__ __launch_bounds__(512, 4) void out_gemm_kernel(
    const unsigned short* __restrict__ xb, const unsigned short* __restrict__ wvt,
    const float* __restrict__ wn, const float* __restrict__ bv,
    float* __restrict__ out) {
  __shared__ __align__(16) unsigned short As[2][8192];   // 2 slots x (256r x 32k) = 32 KB
  __shared__ __align__(16) unsigned short Bs[2][8192];   // 2 slots x (256n x 32k) = 32 KB
  __shared__ float wlds[1024];                           // 4 heads x 256 rows

  int tid = threadIdx.x, l = tid & 63, w = tid >> 6;     // 8 waves
  int qd = l >> 4, lm = l & 15;
  int wm = w >> 2, wnx = w & 3;                          // 2M x 4N wave grid

  int id = blockIdx.x;                    // 2048 blocks; XCD swizzle: same g, all 4 ct -> same XCD
  int ct = (id >> 3) & 3;                 // col-tile (256 cols = 4 heads)
  int g  = (id & 7) | ((id >> 5) << 3);   // 0..511 row-tile
  long row0 = (long)g * 256;              // = b*4096 + rt*256
  long b = g >> 4;
  const unsigned short* Ag = xb + row0 * 512;
  const unsigned short* Bg = wvt + (long)ct * 256 * 512;
  int head = ct * 4 + wnx;                // each wave's 64 cols = exactly one head

  // ---- epilogue weights -> LDS (plain loads; visibility via loop barriers) ----
  {
    float w0 = wn[((b * 16 + ct * 4 + (tid >> 8)) << 12) + (row0 & 4095) + (tid & 255)];
    int i1 = tid + 512;
    float w1 = wn[((b * 16 + ct * 4 + (i1 >> 8)) << 12) + (row0 & 4095) + (i1 & 255)];
    wlds[tid] = w0;
    wlds[i1] = w1;
  }

  // ---- staging source pointers (verified micro-line XOR-swizzled layout) ----
  const unsigned short *pa0, *pa1, *pb0, *pb1;
  {
    int pl0 = (w * 2 + 0) * 64 + l;
    int r20 = pl0 >> 3, sub0 = (pl0 & 7) ^ (r20 & 7);
    int ro0 = (r20 * 2 + (sub0 >> 2)) * 512 + (sub0 & 3) * 8;
    pa0 = Ag + ro0;  pb0 = Bg + ro0;
    int pl1 = (w * 2 + 1) * 64 + l;
    int r21 = pl1 >> 3, sub1 = (pl1 & 7) ^ (r21 & 7);
    int ro1 = (r21 * 2 + (sub1 >> 2)) * 512 + (sub1 & 3) * 8;
    pa1 = Ag + ro1;  pb1 = Bg + ro1;
  }

  // ---- fragment LDS byte offsets (verified formula) ----
  int ofsA[8], ofsB[4];
  #pragma unroll
  for (int mi = 0; mi < 8; ++mi) {
    int m = wm * 128 + mi * 16 + lm;
    int gi = (m >> 1) * 8 + (((((m & 1) << 2) | qd)) ^ ((m >> 1) & 7));
    ofsA[mi] = gi * 16;
  }
  #pragma unroll
  for (int ni = 0; ni < 4; ++ni) {
    int n = wnx * 64 + ni * 16 + lm;
    int gi = (n >> 1) * 8 + (((((n & 1) << 2) | qd)) ^ ((n >> 1) & 7));
    ofsB[ni] = gi * 16;
  }

  f32x4 acc[8][4];
  #pragma unroll
  for (int mi = 0; mi < 8; ++mi)
    #pragma unroll
    for (int ni = 0; ni < 4; ++ni) acc[mi][ni] = f32x4{0.f, 0.f, 0.f, 0.f};

  // ---- prologue: stage K-tile 0 into slot 0 ----
  gl2lds16(pa0, &As[0][(w * 2 + 0) * 512]); gl2lds16(pa1, &As[0][(w * 2 + 1) * 512]);
  pa0 += 32; pa1 += 32;
  gl2lds16(pb0, &Bs[0][(w * 2 + 0) * 512]); gl2lds16(pb1, &Bs[0][(w * 2 + 1) * 512]);
  pb0 += 32; pb1 += 32;

  #pragma unroll
  for (int t = 0; t < 16; ++t) {
    // stage(t) complete for every wave; all reads of slot (t+1)&1 are done
    // (they happened at tile t-1, before the previous barrier).
    asm volatile("s_waitcnt vmcnt(0)\n\ts_barrier" ::: "memory");
    const int slot = t & 1;

    if (t < 15) {
      const int ds = slot ^ 1;
      gl2lds16(pa0, &As[ds][(w * 2 + 0) * 512]);
      gl2lds16(pa1, &As[ds][(w * 2 + 1) * 512]);
      pa0 += 32; pa1 += 32;
      gl2lds16(pb0, &Bs[ds][(w * 2 + 0) * 512]);
      gl2lds16(pb1, &Bs[ds][(w * 2 + 1) * 512]);
      pb0 += 32; pb1 += 32;
    }

    const char* aB = (const char*)&As[slot][0];
    const char* bB = (const char*)&Bs[slot][0];

    short8 bf[4];
    #pragma unroll
    for (int ni = 0; ni < 4; ++ni) bf[ni] = *(const short8*)(bB + ofsB[ni]);
    short8 af0[4];
    #pragma unroll
    for (int mi = 0; mi < 4; ++mi) af0[mi] = *(const short8*)(aB + ofsA[mi]);
    __builtin_amdgcn_s_setprio(1);
    #pragma unroll
    for (int mi = 0; mi < 4; ++mi)
      #pragma unroll
      for (int ni = 0; ni < 4; ++ni)
        acc[mi][ni] = __builtin_amdgcn_mfma_f32_16x16x32_bf16(af0[mi], bf[ni], acc[mi][ni], 0, 0, 0);
    __builtin_amdgcn_s_setprio(0);

    short8 af1[4];
    #pragma unroll
    for (int mi = 0; mi < 4; ++mi) af1[mi] = *(const short8*)(aB + ofsA[mi + 4]);
    __builtin_amdgcn_s_setprio(1);
    #pragma unroll
    for (int mi = 0; mi < 4; ++mi)
      #pragma unroll
      for (int ni = 0; ni < 4; ++ni)
        acc[mi + 4][ni] = __builtin_amdgcn_mfma_f32_16x16x32_bf16(af1[mi], bf[ni], acc[mi + 4][ni], 0, 0, 0);
    __builtin_amdgcn_s_setprio(0);
  }

  // ---- epilogue: out[b,h,v] += sum_rows wn[b,h,s] * tanh(acc + bv) ----
  float bias[4];
  #pragma unroll
  for (int ni = 0; ni < 4; ++ni) bias[ni] = bv[head * 64 + ni * 16 + lm];
  float res[4] = {0.f, 0.f, 0.f, 0.f};
  #pragma unroll
  for (int mi = 0; mi < 8; ++mi) {
    int rb = wm * 128 + mi * 16 + qd * 4;
    float w0 = wlds[wnx * 256 + rb + 0];
    float w1 = wlds[wnx * 256 + rb + 1];
    float w2 = wlds[wnx * 256 + rb + 2];
    float w3 = wlds[wnx * 256 + rb + 3];
    #pragma unroll
    for (int ni = 0; ni < 4; ++ni) {
      f32x4 c = acc[mi][ni];
      res[ni] += w0 * fast_tanh(c[0] + bias[ni]) + w1 * fast_tanh(c[1] + bias[ni])
               + w2 * fast_tanh(c[2] + bias[ni]) + w3 * fast_tanh(c[3] + bias[ni]);
    }
  }
  #pragma unroll
  for (int ni = 0; ni < 4; ++ni) {
    float v = res[ni];
    v += __shfl_xor(v, 16, 64);
    v += __shfl_xor(v, 32, 64);
    if (qd == 0)
      atomicAdd(&out[b * 1024 + head * 64 + ni * 16 + lm], v);
  }
}

// ---------- launch ----------
extern "C" void kernel_launch(void* const* d_in, const int* in_sizes, int n_in,
                              void* d_out, int out_size, void* d_ws, size_t ws_size,
                              hipStream_t stream) {
  const float* kv = (const float*)d_in[0];
  const float* Wk = (const float*)d_in[1];
  // d_in[2] = b_k : constant over softmax axis -> cancels, unused
  const float* Wv = (const float*)d_in[3];
  const float* bv = (const float*)d_in[4];
  const float* q  = (const float*)d_in[5];
  float* out = (float*)d_out;

  char* ws = (char*)d_ws;
  unsigned short* xb  = (unsigned short*)(ws);                       // 128 MB
  unsigned short* wqb = (unsigned short*)(ws + 134217728);           // 16 KB
  unsigned short* wvt = (unsigned short*)(ws + 134217728 + 16384);   // 1 MB
  float* dotbuf = (float*)(ws + 134217728 + 16384 + 1048576);        // 8 MB

  hipMemsetAsync(d_out, 0, 32768 * sizeof(float), stream);
  prep_kernel<<<160, 256, 0, stream>>>(Wk, q, Wv, wqb, wvt);
  dot_kernel<<<1024, 256, 0, stream>>>(kv, wqb, xb, dotbuf);
  softmax_kernel<<<512, 256, 0, stream>>>(dotbuf);
  out_gemm_kernel<<<2048, 512, 0, stream>>>(xb, wvt, dotbuf, bv, out);
}

// Round 3
// 576.165 us; speedup vs baseline: 2.9758x; 2.9758x over previous
//
#include <hip/hip_runtime.h>
#include <cstdint>

using short8 = __attribute__((ext_vector_type(8))) short;
using f32x4  = __attribute__((ext_vector_type(4))) float;

// ---------- helpers ----------
__device__ __forceinline__ unsigned short bf16rne(float f) {
  unsigned int u = __float_as_uint(f);
  unsigned int r = u + 0x7fffu + ((u >> 16) & 1u);
  return (unsigned short)(r >> 16);
}

__device__ __forceinline__ void gl2lds16(const void* g, void* s) {
  auto gp = reinterpret_cast<const __attribute__((address_space(1))) unsigned int*>(
      reinterpret_cast<uintptr_t>(g));
  auto sp = reinterpret_cast<__attribute__((address_space(3))) unsigned int*>(
      (uint32_t)reinterpret_cast<uintptr_t>(s));
  __builtin_amdgcn_global_load_lds(gp, sp, 16, 0, 0);
}

__device__ __forceinline__ float fast_tanh(float x) {
  float e = __expf(2.0f * x);
  return 1.0f - 2.0f / (e + 1.0f);
}

// ---------- K0: fold Wq = W_k @ q (bf16 [16][512]); Wvt = W_v^T (bf16 [1024][512]) ----------
__global__ __launch_bounds__(256) void prep_kernel(
    const float* __restrict__ Wk, const float* __restrict__ q,
    const float* __restrict__ Wv,
    unsigned short* __restrict__ wqb, unsigned short* __restrict__ wvt) {
  __shared__ float T[64 * 65];
  int bid = blockIdx.x;
  if (bid < 32) {
    int idx = bid * 256 + threadIdx.x;   // 0..8191
    int n = idx >> 9, c = idx & 511;
    const float* wrow = Wk + (long)c * 1024 + n * 64;
    const float* qrow = q + n * 64;
    float s = 0.f;
    #pragma unroll 8
    for (int k = 0; k < 64; ++k) s += wrow[k] * qrow[k];
    wqb[n * 512 + c] = bf16rne(s);
  } else {
    int t = bid - 32;                    // 0..127
    int tc = t & 7, tl = t >> 3;
    int c0 = tc * 64, l0 = tl * 64;
    int j = threadIdx.x & 63, i0 = threadIdx.x >> 6;
    #pragma unroll
    for (int ii = 0; ii < 16; ++ii) {
      int i = i0 * 16 + ii;
      T[i * 65 + j] = Wv[(long)(c0 + i) * 1024 + l0 + j];
    }
    __syncthreads();
    #pragma unroll
    for (int ii = 0; ii < 16; ++ii) {
      int jj = i0 * 16 + ii;
      wvt[(long)(l0 + jj) * 512 + c0 + j] = bf16rne(T[j * 65 + jj]);
    }
  }
}

// ---------- K2: fused cvt + dot, 1-barrier async pipeline (unchanged) ----------
__global__ __launch_bounds__(256) void dot_kernel(
    const float* __restrict__ kv, const unsigned short* __restrict__ wqb,
    unsigned short* __restrict__ xb, float* __restrict__ dotbuf) {
  __shared__ __align__(16) float AsF[2][128 * 64];          // 2 x 32 KB
  __shared__ __align__(16) unsigned short Ws[16 * 512];     // 16 KB
  int tid = threadIdx.x, l = tid & 63, w = tid >> 6;
  long row0 = (long)blockIdx.x * 128;
  int qd = l >> 4, lm = l & 15;

  for (int j = 0; j < 4; ++j) {
    int n = w * 4 + j;
    gl2lds16(wqb + n * 512 + ((l ^ (n & 7)) * 8), &Ws[n * 512]);
  }

  auto dmaA = [&](int it, int buf) {
    #pragma unroll
    for (int j = 0; j < 8; ++j) {
      int g = (w * 8 + j) * 64 + l;
      int r = g >> 4, c = g & 15;
      int cc = c ^ (r & 14);
      gl2lds16(kv + (row0 + r) * 512 + it * 64 + cc * 4, &AsF[buf][(w * 8 + j) * 256]);
    }
  };

  f32x4 acc[2];
  acc[0] = f32x4{0.f, 0.f, 0.f, 0.f};
  acc[1] = f32x4{0.f, 0.f, 0.f, 0.f};

  dmaA(0, 0);
  for (int it = 0; it < 8; ++it) {
    __syncthreads();
    if (it < 7) dmaA(it + 1, (it + 1) & 1);
    const float* base = &AsF[it & 1][0];
    #pragma unroll
    for (int mi = 0; mi < 2; ++mi) {
      int m = w * 32 + mi * 16 + lm;
      int s = m & 14;
      #pragma unroll
      for (int k32 = 0; k32 < 2; ++k32) {
        int fc = k32 * 8 + qd * 2;
        float4 fa = *(const float4*)&base[(m * 16 + (fc ^ s)) * 4];
        float4 fb = *(const float4*)&base[(m * 16 + ((fc + 1) ^ s)) * 4];
        short8 h;
        h[0] = bf16rne(fa.x); h[1] = bf16rne(fa.y); h[2] = bf16rne(fa.z); h[3] = bf16rne(fa.w);
        h[4] = bf16rne(fb.x); h[5] = bf16rne(fb.y); h[6] = bf16rne(fb.z); h[7] = bf16rne(fb.w);
        *(short8*)&xb[(row0 + m) * 512 + it * 64 + k32 * 32 + qd * 8] = h;
        int cl = it * 8 + k32 * 4 + qd;
        short8 bfrag = *(const short8*)&Ws[lm * 512 + ((cl ^ (lm & 7)) * 8)];
        acc[mi] = __builtin_amdgcn_mfma_f32_16x16x32_bf16(h, bfrag, acc[mi], 0, 0, 0);
      }
    }
  }
  #pragma unroll
  for (int mi = 0; mi < 2; ++mi) {
    long rg = row0 + w * 32 + mi * 16 + qd * 4;
    long b = rg >> 12;
    long s = rg & 4095;
    *(f32x4*)&dotbuf[((b * 16 + lm) << 12) + s] = acc[mi];
  }
}

// ---------- K3: softmax over s per (b,n), normalize in place (unchanged) ----------
__global__ __launch_bounds__(256) void softmax_kernel(float* __restrict__ dotbuf) {
  long bn = blockIdx.x;
  float4* p = (float4*)(dotbuf + bn * 4096);
  int tid = threadIdx.x;
  int l = tid & 63, w = tid >> 6;
  float4 v[4];
  float mx = -1e30f;
  #pragma unroll
  for (int i = 0; i < 4; ++i) {
    v[i] = p[tid + i * 256];
    mx = fmaxf(mx, fmaxf(fmaxf(v[i].x, v[i].y), fmaxf(v[i].z, v[i].w)));
  }
  for (int o = 32; o; o >>= 1) mx = fmaxf(mx, __shfl_xor(mx, o, 64));
  __shared__ float redm[4];
  __shared__ float reds[4];
  if (l == 0) redm[w] = mx;
  __syncthreads();
  mx = fmaxf(fmaxf(redm[0], redm[1]), fmaxf(redm[2], redm[3]));
  float s = 0.f;
  #pragma unroll
  for (int i = 0; i < 4; ++i) {
    v[i].x = __expf(v[i].x - mx); v[i].y = __expf(v[i].y - mx);
    v[i].z = __expf(v[i].z - mx); v[i].w = __expf(v[i].w - mx);
    s += v[i].x + v[i].y + v[i].z + v[i].w;
  }
  for (int o = 32; o; o >>= 1) s += __shfl_xor(s, o, 64);
  if (l == 0) reds[w] = s;
  __syncthreads();
  s = reds[0] + reds[1] + reds[2] + reds[3];
  float inv = 1.0f / s;
  #pragma unroll
  for (int i = 0; i < 4; ++i) {
    v[i].x *= inv; v[i].y *= inv; v[i].z *= inv; v[i].w *= inv;
    p[tid + i * 256] = v[i];
  }
}

// ---------- K4: value GEMM + tanh + weighted reduce ----------
// R3 STRUCTURE: faithful m201-style 8-phase schedule (T2+T3+T4+T5).
//   R2's launch_bounds(512,4) spilled the 128-reg accumulator (WRITE_SIZE
//   3.85 GB scratch) -> reverted to (512,2). R0/R1 both scored ~676 TF, the
//   documented 2-phase-schedule ceiling; occupancy is NOT the lever (m201:
//   62% MfmaUtil at 1 block/CU, 8 waves). This kernel ports the 8-phase
//   interleave: BM=BN=256, BK=64 (2 verified 16KB sub-blocks), 8 waves
//   (2M x 4N), per-wave 128x64. Per BK=64 tile: 4 phases, each =
//   { 4-8 ds_read_b128 frags | issue ONE half-tile stage (2 gl2lds16) |
//     s_barrier | lgkmcnt(0) | setprio(1) 16 MFMA setprio(0) | s_barrier }.
//   Counted vmcnt(4) at P1/P3 only (never 0 mid-loop); steady state keeps
//   8 loads (2 half-tiles) in flight, >= 1 full tile of latency lead.
//   Wait ledger: at t.P1 outstanding = {A1(t),B1(t),A0(t+1),B0(t+1)} = 8
//   loads -> vmcnt(4) drains A1(t),B1(t) (needed by t.P2 reads, after this
//   barrier). At t.P3 outstanding = 8 of tile t+1 -> vmcnt(4) drains
//   A0(t+1),B0(t+1) (needed by (t+1).P0). Tail t=7: vmcnt(0) at P1.
//   LDS 128 KB (2 slots x (32KB A + 32KB B)) + 4 KB wlds -> 1 block/CU.
//   All swizzle/fragment/epilogue math bit-identical to verified R0/R1.
__global__ __launch_bounds__(512, 2) void out_gemm_kernel(
    const unsigned short* __restrict__ xb, const unsigned short* __restrict__ wvt,
    const float* __restrict__ wn, const float* __restrict__ bv,
    float* __restrict__ out) {
  __shared__ __align__(16) unsigned short As[2][2][8192];  // [slot][kkhalf][256r x 32k] = 64 KB
  __shared__ __align__(16) unsigned short Bs[2][2][8192];  // 64 KB
  __shared__ float wlds[1024];                             // 4 heads x 256 rows

  int tid = threadIdx.x, l = tid & 63, w = tid >> 6;       // 8 waves
  int qd = l >> 4, lm = l & 15;
  int wm = w >> 2, wnx = w & 3;                            // 2M x 4N wave grid

  int id = blockIdx.x;                    // 2048 blocks; same g, all 4 ct -> same XCD
  int ct = (id >> 3) & 3;                 // col-tile (256 cols = 4 heads)
  int g  = (id & 7) | ((id >> 5) << 3);   // 0..511 row-tile
  long row0 = (long)g * 256;              // = b*4096 + rt*256
  long b = g >> 4;
  const unsigned short* Ag = xb + row0 * 512;
  const unsigned short* Bg = wvt + (long)ct * 256 * 512;
  int head = ct * 4 + wnx;                // each wave's 64 cols = exactly one head

  // ---- epilogue weights -> LDS FIRST (their value-waits retire before any
  //      staging is issued, keeping the manual vmcnt ledger clean) ----
  {
    float w0 = wn[((b * 16 + ct * 4 + (tid >> 8)) << 12) + (row0 & 4095) + (tid & 255)];
    int i1 = tid + 512;
    float w1 = wn[((b * 16 + ct * 4 + (i1 >> 8)) << 12) + (row0 & 4095) + (i1 & 255)];
    wlds[tid] = w0;
    wlds[i1] = w1;
  }

  // ---- staging source pointers (verified micro-line XOR-swizzled layout).
  //      16KB sub-block j covers K-cols [32j,32j+32): src offset = t*64+kk*32. ----
  const unsigned short *pa0, *pa1, *pb0, *pb1;
  {
    int pl0 = (w * 2 + 0) * 64 + l;
    int r20 = pl0 >> 3, sub0 = (pl0 & 7) ^ (r20 & 7);
    int ro0 = (r20 * 2 + (sub0 >> 2)) * 512 + (sub0 & 3) * 8;
    pa0 = Ag + ro0;  pb0 = Bg + ro0;
    int pl1 = (w * 2 + 1) * 64 + l;
    int r21 = pl1 >> 3, sub1 = (pl1 & 7) ^ (r21 & 7);
    int ro1 = (r21 * 2 + (sub1 >> 2)) * 512 + (sub1 & 3) * 8;
    pa1 = Ag + ro1;  pb1 = Bg + ro1;
  }
  int d0 = (w * 2 + 0) * 512, d1 = (w * 2 + 1) * 512;   // LDS line dests

  // ---- fragment LDS byte offsets (verified formula) ----
  int ofsA[8], ofsB[4];
  #pragma unroll
  for (int mi = 0; mi < 8; ++mi) {
    int m = wm * 128 + mi * 16 + lm;
    int gi = (m >> 1) * 8 + (((((m & 1) << 2) | qd)) ^ ((m >> 1) & 7));
    ofsA[mi] = gi * 16;
  }
  #pragma unroll
  for (int ni = 0; ni < 4; ++ni) {
    int n = wnx * 64 + ni * 16 + lm;
    int gi = (n >> 1) * 8 + (((((n & 1) << 2) | qd)) ^ ((n >> 1) & 7));
    ofsB[ni] = gi * 16;
  }

  f32x4 acc[8][4];
  #pragma unroll
  for (int mi = 0; mi < 8; ++mi)
    #pragma unroll
    for (int ni = 0; ni < 4; ++ni) acc[mi][ni] = f32x4{0.f, 0.f, 0.f, 0.f};

  // ---- prologue: stage all 4 halves of tile 0 (order: A0,B0,A1,B1) ----
  gl2lds16(pa0,      &As[0][0][d0]); gl2lds16(pa1,      &As[0][0][d1]);
  gl2lds16(pb0,      &Bs[0][0][d0]); gl2lds16(pb1,      &Bs[0][0][d1]);
  gl2lds16(pa0 + 32, &As[0][1][d0]); gl2lds16(pa1 + 32, &As[0][1][d1]);
  gl2lds16(pb0 + 32, &Bs[0][1][d0]); gl2lds16(pb1 + 32, &Bs[0][1][d1]);
  asm volatile("s_waitcnt vmcnt(4)" ::: "memory");   // A0(0),B0(0) done
  __syncthreads();

  #pragma unroll
  for (int t = 0; t < 8; ++t) {
    const int slot = t & 1, ds = slot ^ 1;
    const char* a0 = (const char*)&As[slot][0][0];
    const char* a1 = (const char*)&As[slot][1][0];
    const char* b0 = (const char*)&Bs[slot][0][0];
    const char* b1 = (const char*)&Bs[slot][1][0];
    const int so = (t + 1) * 64;   // next-tile source col offset (elements)

    // ================= P0: frags(A-low kk0, B kk0); stage A-half0(t+1) =====
    short8 bf0[4], af[4];
    #pragma unroll
    for (int ni = 0; ni < 4; ++ni) bf0[ni] = *(const short8*)(b0 + ofsB[ni]);
    #pragma unroll
    for (int mi = 0; mi < 4; ++mi) af[mi] = *(const short8*)(a0 + ofsA[mi]);
    if (t < 7) {
      gl2lds16(pa0 + so, &As[ds][0][d0]);
      gl2lds16(pa1 + so, &As[ds][0][d1]);
    }
    asm volatile("s_barrier" ::: "memory");
    asm volatile("s_waitcnt lgkmcnt(0)" ::: "memory");
    __builtin_amdgcn_s_setprio(1);
    #pragma unroll
    for (int mi = 0; mi < 4; ++mi)
      #pragma unroll
      for (int ni = 0; ni < 4; ++ni)
        acc[mi][ni] = __builtin_amdgcn_mfma_f32_16x16x32_bf16(af[mi], bf0[ni], acc[mi][ni], 0, 0, 0);
    __builtin_amdgcn_s_setprio(0);
    asm volatile("s_barrier" ::: "memory");

    // ================= P1: frags(A-high kk0); stage B-half0(t+1); vmcnt =====
    #pragma unroll
    for (int mi = 0; mi < 4; ++mi) af[mi] = *(const short8*)(a0 + ofsA[mi + 4]);
    if (t < 7) {
      gl2lds16(pb0 + so, &Bs[ds][0][d0]);
      gl2lds16(pb1 + so, &Bs[ds][0][d1]);
      asm volatile("s_waitcnt vmcnt(4)" ::: "memory");   // A1(t),B1(t) done
    } else {
      asm volatile("s_waitcnt vmcnt(0)" ::: "memory");   // tail drain
    }
    asm volatile("s_barrier" ::: "memory");
    asm volatile("s_waitcnt lgkmcnt(0)" ::: "memory");
    __builtin_amdgcn_s_setprio(1);
    #pragma unroll
    for (int mi = 0; mi < 4; ++mi)
      #pragma unroll
      for (int ni = 0; ni < 4; ++ni)
        acc[mi + 4][ni] = __builtin_amdgcn_mfma_f32_16x16x32_bf16(af[mi], bf0[ni], acc[mi + 4][ni], 0, 0, 0);
    __builtin_amdgcn_s_setprio(0);
    asm volatile("s_barrier" ::: "memory");

    // ================= P2: frags(A-low kk1, B kk1); stage A-half1(t+1) =====
    short8 bf1[4];
    #pragma unroll
    for (int ni = 0; ni < 4; ++ni) bf1[ni] = *(const short8*)(b1 + ofsB[ni]);
    #pragma unroll
    for (int mi = 0; mi < 4; ++mi) af[mi] = *(const short8*)(a1 + ofsA[mi]);
    if (t < 7) {
      gl2lds16(pa0 + so + 32, &As[ds][1][d0]);
      gl2lds16(pa1 + so + 32, &As[ds][1][d1]);
    }
    asm volatile("s_barrier" ::: "memory");
    asm volatile("s_waitcnt lgkmcnt(0)" ::: "memory");
    __builtin_amdgcn_s_setprio(1);
    #pragma unroll
    for (int mi = 0; mi < 4; ++mi)
      #pragma unroll
      for (int ni = 0; ni < 4; ++ni)
        acc[mi][ni] = __builtin_amdgcn_mfma_f32_16x16x32_bf16(af[mi], bf1[ni], acc[mi][ni], 0, 0, 0);
    __builtin_amdgcn_s_setprio(0);
    asm volatile("s_barrier" ::: "memory");

    // ================= P3: frags(A-high kk1); stage B-half1(t+1); vmcnt =====
    #pragma unroll
    for (int mi = 0; mi < 4; ++mi) af[mi] = *(const short8*)(a1 + ofsA[mi + 4]);
    if (t < 7) {
      gl2lds16(pb0 + so + 32, &Bs[ds][1][d0]);
      gl2lds16(pb1 + so + 32, &Bs[ds][1][d1]);
      asm volatile("s_waitcnt vmcnt(4)" ::: "memory");   // A0(t+1),B0(t+1) done
    }
    asm volatile("s_barrier" ::: "memory");
    asm volatile("s_waitcnt lgkmcnt(0)" ::: "memory");
    __builtin_amdgcn_s_setprio(1);
    #pragma unroll
    for (int mi = 0; mi < 4; ++mi)
      #pragma unroll
      for (int ni = 0; ni < 4; ++ni)
        acc[mi + 4][ni] = __builtin_amdgcn_mfma_f32_16x16x32_bf16(af[mi], bf1[ni], acc[mi + 4][ni], 0, 0, 0);
    __builtin_amdgcn_s_setprio(0);
    asm volatile("s_barrier" ::: "memory");
  }

  // ---- epilogue: out[b,h,v] += sum_rows wn[b,h,s] * tanh(acc + bv) ----
  __syncthreads();   // wlds visible (already was via loop barriers)

  float bias[4];
  #pragma unroll
  for (int ni = 0; ni < 4; ++ni) bias[ni] = bv[head * 64 + ni * 16 + lm];
  float res[4] = {0.f, 0.f, 0.f, 0.f};
  #pragma unroll
  for (int mi = 0; mi < 8; ++mi) {
    int rb = wm * 128 + mi * 16 + qd * 4;
    float w0 = wlds[wnx * 256 + rb + 0];
    float w1 = wlds[wnx * 256 + rb + 1];
    float w2 = wlds[wnx * 256 + rb + 2];
    float w3 = wlds[wnx * 256 + rb + 3];
    #pragma unroll
    for (int ni = 0; ni < 4; ++ni) {
      f32x4 c = acc[mi][ni];
      res[ni] += w0 * fast_tanh(c[0] + bias[ni]) + w1 * fast_tanh(c[1] + bias[ni])
               + w2 * fast_tanh(c[2] + bias[ni]) + w3 * fast_tanh(c[3] + bias[ni]);
    }
  }
  #pragma unroll
  for (int ni = 0; ni < 4; ++ni) {
    float v = res[ni];
    v += __shfl_xor(v, 16, 64);
    v += __shfl_xor(v, 32, 64);
    if (qd == 0)
      atomicAdd(&out[b * 1024 + head * 64 + ni * 16 + lm], v);
  }
}

// ---------- launch ----------
extern "C" void kernel_launch(void* const* d_in, const int* in_sizes, int n_in,
                              void* d_out, int out_size, void* d_ws, size_t ws_size,
                              hipStream_t stream) {
  const float* kv = (const float*)d_in[0];
  const float* Wk = (const float*)d_in[1];
  // d_in[2] = b_k : constant over softmax axis -> cancels, unused
  const float* Wv = (const float*)d_in[3];
  const float* bv = (const float*)d_in[4];
  const float* q  = (const float*)d_in[5];
  float* out = (float*)d_out;

  char* ws = (char*)d_ws;
  unsigned short* xb  = (unsigned short*)(ws);                       // 128 MB
  unsigned short* wqb = (unsigned short*)(ws + 134217728);           // 16 KB
  unsigned short* wvt = (unsigned short*)(ws + 134217728 + 16384);   // 1 MB
  float* dotbuf = (float*)(ws + 134217728 + 16384 + 1048576);        // 8 MB

  hipMemsetAsync(d_out, 0, 32768 * sizeof(float), stream);
  prep_kernel<<<160, 256, 0, stream>>>(Wk, q, Wv, wqb, wvt);
  dot_kernel<<<1024, 256, 0, stream>>>(kv, wqb, xb, dotbuf);
  softmax_kernel<<<512, 256, 0, stream>>>(dotbuf);
  out_gemm_kernel<<<2048, 512, 0, stream>>>(xb, wvt, dotbuf, bv, out);
}